// Round 7
// baseline (39.812 us; speedup 1.0000x reference)
//
#include <hip/hip_runtime.h>
#include <hip/hip_bf16.h>

#define M 256
#define NOUT 1024
#define KTOT 16384
#define RANK 16
#define NKC 32          // split-K blocks
#define KCHUNK 512      // K per gemm block (2 LDS phases of 256)

typedef __attribute__((ext_vector_type(8)))  short bf16x8_t;
typedef __attribute__((ext_vector_type(4)))  float f32x4_t;
typedef __attribute__((ext_vector_type(16))) float f32x16_t;
typedef __attribute__((ext_vector_type(8)))  unsigned short u16x8_t;

static __device__ __forceinline__ unsigned short f2bf(float f) {
  unsigned u = __builtin_bit_cast(unsigned, f);
  u += 0x7FFFu + ((u >> 16) & 1u);   // round-to-nearest-even
  return (unsigned short)(u >> 16);
}
static __device__ __forceinline__ float bf2f(unsigned short h) {
  unsigned u = ((unsigned)h) << 16;
  return __builtin_bit_cast(float, u);
}
static __device__ __forceinline__ bf16x8_t mkfrag(float4 a, float4 b) {
  bf16x8_t r;
  r[0] = (short)f2bf(a.x); r[1] = (short)f2bf(a.y);
  r[2] = (short)f2bf(a.z); r[3] = (short)f2bf(a.w);
  r[4] = (short)f2bf(b.x); r[5] = (short)f2bf(b.y);
  r[6] = (short)f2bf(b.z); r[7] = (short)f2bf(b.w);
  return r;
}

// X stored in 256-k chunks (64 chunks), slot-swizzled for conflict-free
// B-fragment ds_read_b128:
//   element (b,k): chunk = k>>8, slot = (k&255)>>3 (0..31), el = k&7
//   pos = ((chunk*256 + b)*32 + (slot ^ (b&31)))*8 + el        (bf16)
// Staged linearly into LDS; read slot for k-step TT is (2*TT+l5) ^ (b&31):
// 32 lanes of a row-group hit 32 distinct 16B slots -> 2-way only (free).
__global__ __launch_bounds__(256) void build_x_kernel(
    const float* __restrict__ input, const float* __restrict__ coef,
    unsigned short* __restrict__ X)
{
  int idx = blockIdx.x * 256 + threadIdx.x;   // idx = b*1024 + i
  int b = idx >> 10, i = idx & 1023;
  float in = input[idx];
  const float* c = coef + b * RANK;
  u16x8_t lo, hi;                              // k = i*16 + r
  #pragma unroll
  for (int r = 0; r < 8; ++r) lo[r] = f2bf(in * c[r]);
  #pragma unroll
  for (int r = 0; r < 8; ++r) hi[r] = f2bf(in * c[8 + r]);
  int chunk = i >> 4;
  int s0 = (i & 15) * 2;         // slots s0 (r 0..7), s0+1 (r 8..15)
  int sw = b & 31;
  size_t base = ((size_t)chunk * 256 + b) * 256;   // shorts
  *(u16x8_t*)(X + base + (size_t)((s0    ) ^ sw) * 8) = lo;
  *(u16x8_t*)(X + base + (size_t)((s0 + 1) ^ sw) * 8) = hi;
}

// out^T GEMM: part[kc][o][b] (bf16) = sum_{k in chunk kc} W[o,k] * X[b,k]
// via mfma_f32_32x32x16_bf16 with A = W-frag (row=l&31 -> o, k=(l>>5)*8+j,
// 32 B contiguous fp32 per lane, loaded GLOBAL->REG, cvt at use) and
// B = X-frag from LDS (col=l&31 -> b). Block: 128 o x 256 b x K=512.
// 4 waves, wave w owns o-rows [ot*128+w*32, +32), each A-frag feeds 8 MFMAs
// (b-tiles j=0..7). X k-slice (128 KB) resident in LDS, loaded once per
// 256-k phase -> NO per-iter staging, NO in-loop barriers (3 barriers total).
// W prefetch: 8 named register slots, rotation, 8 k-steps ahead.
__global__ __launch_bounds__(256, 1) void gemm_kernel(
    const unsigned short* __restrict__ X, const float* __restrict__ W,
    unsigned short* __restrict__ part)
{
  __shared__ unsigned short Xs[256 * 256];   // 128 KB: [b][32 slots * 8]

  const int tid = threadIdx.x;
  const int w = tid >> 6, lane = tid & 63;
  const int l31 = lane & 31, l5 = lane >> 5;

  // XCD co-location: 8 ot-blocks sharing X chunk kc -> same XCD
  // (lin%8 = kc>>2; per XCD: 4 kc x 2 chunks x 128 KB = 1 MB, L2-resident)
  const int lin = blockIdx.x;
  const int kc = 4 * (lin & 7) + (lin >> 6);
  const int ot = (lin >> 3) & 7;

  const float* wrow = W + (size_t)(ot * 128 + w * 32 + l31) * KTOT
                        + kc * KCHUNK + l5 * 8;

  f32x16_t acc[8];
  #pragma unroll
  for (int j = 0; j < 8; ++j) acc[j] = (f32x16_t)(0.0f);

  float4 r0a, r0b, r1a, r1b, r2a, r2b, r3a, r3b,
         r4a, r4b, r5a, r5b, r6a, r6b, r7a, r7b;

  #define ISSUE(S, T) { r##S##a = *(const float4*)(wrow + 16 * (T));          \
                        r##S##b = *(const float4*)(wrow + 16 * (T) + 4); }

  #define STAGE(PH)                                                           \
    {                                                                         \
      const unsigned short* src = X + (size_t)(kc * 2 + (PH)) * 65536;        \
      _Pragma("unroll")                                                       \
      for (int j = 0; j < 32; ++j) {                                          \
        __builtin_amdgcn_global_load_lds(                                     \
            (const __attribute__((address_space(1))) unsigned int*)           \
                (src + (size_t)(j * 256 + tid) * 8),                          \
            (__attribute__((address_space(3))) unsigned int*)                 \
                (&Xs[(j * 256 + tid) * 8]),                                   \
            16, 0, 0);                                                        \
      }                                                                       \
    }

  #define COMPA(AF, TT)                                                       \
    {                                                                         \
      __builtin_amdgcn_s_setprio(1);                                          \
      _Pragma("unroll")                                                       \
      for (int j = 0; j < 8; ++j) {                                           \
        bf16x8_t bf = *(const bf16x8_t*)                                      \
            &Xs[(j * 32 + l31) * 256 + (((2 * (TT) + l5) ^ l31) * 8)];        \
        acc[j] = __builtin_amdgcn_mfma_f32_32x32x16_bf16(AF, bf, acc[j],      \
                                                         0, 0, 0);            \
      }                                                                       \
      __builtin_amdgcn_s_setprio(0);                                          \
    }

  #define STEPI(S, TT, TN)                                                    \
    { bf16x8_t af = mkfrag(r##S##a, r##S##b); ISSUE(S, TN) COMPA(af, TT) }
  #define STEPN(S, TT)                                                        \
    { bf16x8_t af = mkfrag(r##S##a, r##S##b); COMPA(af, TT) }

  // ---- phase 0: stage X chunk 2kc, prefetch W frags 0..7 ----
  STAGE(0)
  ISSUE(0, 0) ISSUE(1, 1) ISSUE(2, 2) ISSUE(3, 3)
  ISSUE(4, 4) ISSUE(5, 5) ISSUE(6, 6) ISSUE(7, 7)
  __syncthreads();

  STEPI(0, 0, 8)  STEPI(1, 1, 9)  STEPI(2, 2, 10) STEPI(3, 3, 11)
  STEPI(4, 4, 12) STEPI(5, 5, 13) STEPI(6, 6, 14) STEPI(7, 7, 15)
  STEPN(0, 8)  STEPN(1, 9)  STEPN(2, 10) STEPN(3, 11)
  STEPN(4, 12) STEPN(5, 13) STEPN(6, 14) STEPN(7, 15)

  // ---- boundary: all phase-0 reads done; restage LDS, re-warm W ----
  __syncthreads();
  STAGE(1)
  ISSUE(0, 16) ISSUE(1, 17) ISSUE(2, 18) ISSUE(3, 19)
  ISSUE(4, 20) ISSUE(5, 21) ISSUE(6, 22) ISSUE(7, 23)
  __syncthreads();

  STEPI(0, 0, 24) STEPI(1, 1, 25) STEPI(2, 2, 26) STEPI(3, 3, 27)
  STEPI(4, 4, 28) STEPI(5, 5, 29) STEPI(6, 6, 30) STEPI(7, 7, 31)
  STEPN(0, 8)  STEPN(1, 9)  STEPN(2, 10) STEPN(3, 11)
  STEPN(4, 12) STEPN(5, 13) STEPN(6, 14) STEPN(7, 15)

  // ---- epilogue: D layout col(b)=l&31, row(o)=(q&3)+8*(q>>2)+4*l5 ----
  unsigned short* p = part + (size_t)kc * (NOUT * 256);
  #pragma unroll
  for (int j = 0; j < 8; ++j) {
    #pragma unroll
    for (int q = 0; q < 16; ++q) {
      int o = ot * 128 + w * 32 + (q & 3) + 8 * (q >> 2) + 4 * l5;
      int b = j * 32 + l31;
      p[(size_t)o * 256 + b] = f2bf(acc[j][q]);
    }
  }
  #undef ISSUE
  #undef STAGE
  #undef COMPA
  #undef STEPI
  #undef STEPN
}

// out[b][o] = sum_kc bf2f(part[kc][o][b]) + sum_r bias[o][r]*coef[b][r]
// Block: 8 o-rows x 256 b. Coalesced part reads; LDS transpose; coalesced
// out writes (32 B contiguous per thread).
__global__ __launch_bounds__(256) void reduce_bias_kernel(
    const unsigned short* __restrict__ part, const float* __restrict__ bias,
    const float* __restrict__ coef, float* __restrict__ out)
{
  __shared__ float lds[8 * 256];
  const int t = threadIdx.x;
  const int o = blockIdx.x * 8 + (t >> 5);
  const int b8 = (t & 31) * 8;

  float s[8];
  #pragma unroll
  for (int j = 0; j < 8; ++j) s[j] = 0.f;

  #pragma unroll 8
  for (int kc = 0; kc < NKC; ++kc) {
    u16x8_t v = *(const u16x8_t*)(part + ((size_t)kc * NOUT + o) * 256 + b8);
    #pragma unroll
    for (int j = 0; j < 8; ++j) s[j] += bf2f(v[j]);
  }

  const f32x4_t* br = (const f32x4_t*)(bias + (size_t)o * RANK);
  f32x4_t b0 = br[0], b1 = br[1], b2 = br[2], b3 = br[3];
  #pragma unroll
  for (int j = 0; j < 8; ++j) {
    const f32x4_t* cr = (const f32x4_t*)(coef + (size_t)(b8 + j) * RANK);
    f32x4_t c0 = cr[0], c1 = cr[1], c2 = cr[2], c3 = cr[3];
    float bb = 0.f;
    #pragma unroll
    for (int e = 0; e < 4; ++e)
      bb += b0[e] * c0[e] + b1[e] * c1[e] + b2[e] * c2[e] + b3[e] * c3[e];
    s[j] += bb;
  }

  // transpose 8x256 tile through LDS
  f32x4_t v0, v1;
  v0[0] = s[0]; v0[1] = s[1]; v0[2] = s[2]; v0[3] = s[3];
  v1[0] = s[4]; v1[1] = s[5]; v1[2] = s[6]; v1[3] = s[7];
  *(f32x4_t*)&lds[(t >> 5) * 256 + b8]     = v0;
  *(f32x4_t*)&lds[(t >> 5) * 256 + b8 + 4] = v1;
  __syncthreads();

  const int b = t;
  float g[8];
  #pragma unroll
  for (int j = 0; j < 8; ++j) g[j] = lds[j * 256 + b];
  float4* dst = (float4*)(out + (size_t)b * NOUT + blockIdx.x * 8);
  dst[0] = make_float4(g[0], g[1], g[2], g[3]);
  dst[1] = make_float4(g[4], g[5], g[6], g[7]);
}

extern "C" void kernel_launch(void* const* d_in, const int* in_sizes, int n_in,
                              void* d_out, int out_size, void* d_ws, size_t ws_size,
                              hipStream_t stream) {
  const float* input = (const float*)d_in[0];   // (256, 1024)
  const float* coef  = (const float*)d_in[1];   // (256, 16)
  const float* W     = (const float*)d_in[2];   // (1024, 1024, 16) -> (1024, 16384)
  const float* bias  = (const float*)d_in[3];   // (1024, 16)
  float* out = (float*)d_out;                   // (256, 1024)

  unsigned short* X    = (unsigned short*)d_ws;                               // 8 MiB bf16
  unsigned short* part = (unsigned short*)((char*)d_ws + (size_t)M * KTOT * 2); // 16 MiB bf16

  build_x_kernel<<<(M * 1024) / 256, 256, 0, stream>>>(input, coef, X);
  gemm_kernel<<<256, 256, 0, stream>>>(X, W, part);
  reduce_bias_kernel<<<NOUT / 8, 256, 0, stream>>>(part, bias, coef, out);
}